// Round 4
// baseline (1805.085 us; speedup 1.0000x reference)
//
#include <hip/hip_runtime.h>
#include <hip/hip_bf16.h>

#define D 64
#define RPB 32                 // rows per bucket
#define ACC_ELEMS (RPB * D)    // 2048 floats = 8 KB LDS

typedef unsigned long long ull;

// ---------------- fallback: round-1 atomic kernel ----------------
__global__ __launch_bounds__(256) void spmm_atomic_kernel(
    const float* __restrict__ x,
    const int*   __restrict__ edge_row,
    const int*   __restrict__ edge_col,
    const float* __restrict__ edge_val,
    float*       __restrict__ out,
    int n_edges)
{
    const int gtid = blockIdx.x * blockDim.x + threadIdx.x;
    const int wave = gtid >> 6;
    const int lane = threadIdx.x & 63;
    if (wave >= n_edges) return;
    const int   r = edge_row[wave];
    const int   c = edge_col[wave];
    const float v = edge_val[wave];
    atomicAdd(&out[(size_t)r * D + lane], v * x[(size_t)c * D + lane]);
}

// ---------------- bucket histogram: counts[row>>5]++ ----------------
__global__ void hist_kernel(const int* __restrict__ rows,
                            int* __restrict__ counts, int n_edges)
{
    int i = blockIdx.x * blockDim.x + threadIdx.x;
    if (i < n_edges) atomicAdd(&counts[rows[i] >> 5], 1);
}

// ---------------- single-block exclusive scan over n_buckets (<=8192) ----------------
__global__ __launch_bounds__(1024) void scan_kernel(
    const int* __restrict__ counts,
    int* __restrict__ offsets,   // n_buckets + 1
    int* __restrict__ cursor,    // n_buckets
    int n_buckets, int ipt)      // ipt <= 8
{
    __shared__ int s[1024];
    const int t = threadIdx.x;
    const int base = t * ipt;
    int vexcl[8];
    int sum = 0;
    #pragma unroll
    for (int k = 0; k < 8; ++k) {
        if (k < ipt) {
            int i = base + k;
            int c = (i < n_buckets) ? counts[i] : 0;
            vexcl[k] = sum;
            sum += c;
        }
    }
    s[t] = sum;
    for (int off = 1; off < 1024; off <<= 1) {
        __syncthreads();
        int v = (t >= off) ? s[t - off] : 0;
        __syncthreads();
        s[t] += v;
    }
    const int texcl = s[t] - sum;  // exclusive prefix of this thread's chunk
    #pragma unroll
    for (int k = 0; k < 8; ++k) {
        if (k < ipt) {
            int i = base + k;
            if (i < n_buckets) {
                int o = texcl + vexcl[k];
                offsets[i] = o;
                cursor[i]  = o;
            }
        }
    }
    if (t == 1023) offsets[n_buckets] = s[1023];  // grand total
}

// ---------------- scatter edges into bucket-append streams ----------------
// record = [ val:f32 (hi32) | localrow:bits24-28, col:bits0-23 (lo32) ]
__global__ void scatter_kernel(const int* __restrict__ rows,
                               const int* __restrict__ cols,
                               const float* __restrict__ vals,
                               int* __restrict__ cursor,
                               ull* __restrict__ recs,
                               int n_edges)
{
    int i = blockIdx.x * blockDim.x + threadIdx.x;
    if (i >= n_edges) return;
    const int   r = rows[i];
    const int   c = cols[i];
    const float v = vals[i];
    const int   b = r >> 5;
    const unsigned packed = ((unsigned)(r & 31) << 24) | (unsigned)c;
    const int pos = atomicAdd(&cursor[b], 1);
    recs[pos] = ((ull)__float_as_uint(v) << 32) | (ull)packed;
}

// ---------------- bucket accumulate: one block per bucket ----------------
// Per wave: load 64 records with ONE coalesced per-lane vector load,
// broadcast each via __shfl (v_readlane -> SGPR), gather x 16-wide ILP,
// ds_add into the 8 KB LDS row-tile, write out once, coalesced.
__global__ __launch_bounds__(256) void spmm_bucket_kernel(
    const float* __restrict__ x,
    const int*   __restrict__ offsets,
    const ull*   __restrict__ recs,
    float*       __restrict__ out,
    int n_nodes)
{
    __shared__ float acc[ACC_ELEMS];
    const int t = threadIdx.x;
    const int b = blockIdx.x;

    float4* acc4 = (float4*)acc;
    #pragma unroll
    for (int i = t; i < ACC_ELEMS / 4; i += 256)
        acc4[i] = make_float4(0.f, 0.f, 0.f, 0.f);
    __syncthreads();

    const int bs   = offsets[b];
    const int be   = offsets[b + 1];
    const int lane = t & 63;
    const int w    = t >> 6;

    // waves take interleaved 64-record chunks
    for (int base = bs + w * 64; base < be; base += 256) {
        const int idx = base + lane;
        // pad tail with zero record: v=0 -> adds 0.0f to acc[0*D+lane], harmless
        ull r = (idx < be) ? recs[idx] : 0ull;
        const int nrec = min(64, be - base);

        for (int k0 = 0; k0 < nrec; k0 += 16) {
            float vv[16], xv[16];
            int   aa[16];
            #pragma unroll
            for (int u = 0; u < 16; ++u) {
                const ull rk = __shfl(r, k0 + u);        // broadcast record k
                const unsigned lo = (unsigned)rk;
                vv[u] = __uint_as_float((unsigned)(rk >> 32));
                const int c  = (int)(lo & 0xFFFFFF);
                aa[u] = (int)(lo >> 24) * D + lane;
                xv[u] = x[(size_t)c * D + lane];          // 16 gathers in flight
            }
            #pragma unroll
            for (int u = 0; u < 16; ++u)
                atomicAdd(&acc[aa[u]], vv[u] * xv[u]);
        }
    }
    __syncthreads();

    // coalesced float4 writeback; every out row belongs to exactly one bucket
    const float4* accr = (const float4*)acc;
    float4* out4 = (float4*)out;
    const size_t obase = (size_t)b * (ACC_ELEMS / 4);
    #pragma unroll
    for (int i = t; i < ACC_ELEMS / 4; i += 256) {
        const int row = b * RPB + (i >> 4);
        if (row < n_nodes) out4[obase + i] = accr[i];
    }
}

static inline size_t align16(size_t v) { return (v + 15) & ~(size_t)15; }

extern "C" void kernel_launch(void* const* d_in, const int* in_sizes, int n_in,
                              void* d_out, int out_size, void* d_ws, size_t ws_size,
                              hipStream_t stream)
{
    // setup_inputs order: t, x, edge_row, edge_col, edge_val
    const float* x        = (const float*)d_in[1];
    const int*   edge_row = (const int*)d_in[2];
    const int*   edge_col = (const int*)d_in[3];
    const float* edge_val = (const float*)d_in[4];
    float*       out      = (float*)d_out;

    const int n_edges = in_sizes[2];
    const int n_nodes = out_size / D;
    const int n_buckets = (n_nodes + RPB - 1) / RPB;
    const int ipt = (n_buckets + 1023) / 1024;

    // workspace carve: records first (8B-aligned), then counters
    const size_t off_recs    = 0;                                             // n_edges * 8
    const size_t off_counts  = align16(off_recs + (size_t)n_edges * 8);       // n_buckets ints
    const size_t off_offsets = align16(off_counts + (size_t)n_buckets * 4);   // n_buckets+1 ints
    const size_t off_cursor  = align16(off_offsets + (size_t)(n_buckets + 1) * 4); // n_buckets ints
    const size_t ws_needed   = off_cursor + (size_t)n_buckets * 4;

    if (ws_size < ws_needed || ipt > 8 || n_nodes > (1 << 24)) {
        hipMemsetAsync(out, 0, (size_t)out_size * sizeof(float), stream);
        const int n_blocks = (n_edges + 3) / 4;
        spmm_atomic_kernel<<<n_blocks, 256, 0, stream>>>(
            x, edge_row, edge_col, edge_val, out, n_edges);
        return;
    }

    char* ws = (char*)d_ws;
    ull*  recs    = (ull*)(ws + off_recs);
    int*  counts  = (int*)(ws + off_counts);
    int*  offsets = (int*)(ws + off_offsets);
    int*  cursor  = (int*)(ws + off_cursor);

    hipMemsetAsync(counts, 0, (size_t)n_buckets * sizeof(int), stream);

    const int eb = (n_edges + 255) / 256;
    hist_kernel<<<eb, 256, 0, stream>>>(edge_row, counts, n_edges);
    scan_kernel<<<1, 1024, 0, stream>>>(counts, offsets, cursor, n_buckets, ipt);
    scatter_kernel<<<eb, 256, 0, stream>>>(edge_row, edge_col, edge_val,
                                           cursor, recs, n_edges);
    spmm_bucket_kernel<<<n_buckets, 256, 0, stream>>>(x, offsets, recs, out, n_nodes);
}

// Round 5
// 510.499 us; speedup vs baseline: 3.5359x; 3.5359x over previous
//
#include <hip/hip_runtime.h>
#include <hip/hip_bf16.h>

#define D 64
#define RPB 16                  // rows per bucket (4-bit local row)
#define SORT_CAP 2048           // LDS staging capacity (recs) for in-place bucket sort
#define SCAN_BLOCK 256

typedef unsigned long long ull;

// ---------------- fallback: round-1 atomic kernel ----------------
__global__ __launch_bounds__(256) void spmm_atomic_kernel(
    const float* __restrict__ x,
    const int*   __restrict__ edge_row,
    const int*   __restrict__ edge_col,
    const float* __restrict__ edge_val,
    float*       __restrict__ out,
    int n_edges)
{
    const int gtid = blockIdx.x * blockDim.x + threadIdx.x;
    const int wave = gtid >> 6;
    const int lane = threadIdx.x & 63;
    if (wave >= n_edges) return;
    const int   r = edge_row[wave];
    const int   c = edge_col[wave];
    const float v = edge_val[wave];
    atomicAdd(&out[(size_t)r * D + lane], v * x[(size_t)c * D + lane]);
}

// ---------------- row histogram ----------------
__global__ void hist_kernel(const int* __restrict__ rows,
                            int* __restrict__ counts, int n_edges)
{
    int i = blockIdx.x * blockDim.x + threadIdx.x;
    if (i < n_edges) atomicAdd(&counts[rows[i]], 1);
}

// ---------------- blocked exclusive scan over n = n_nodes+1 ----------------
__global__ void scan_partial_kernel(const int* __restrict__ counts,
                                    int* __restrict__ partials, int n)
{
    __shared__ int s[SCAN_BLOCK];
    int i = blockIdx.x * SCAN_BLOCK + threadIdx.x;
    s[threadIdx.x] = (i < n) ? counts[i] : 0;
    __syncthreads();
    for (int off = SCAN_BLOCK / 2; off > 0; off >>= 1) {
        if (threadIdx.x < off) s[threadIdx.x] += s[threadIdx.x + off];
        __syncthreads();
    }
    if (threadIdx.x == 0) partials[blockIdx.x] = s[0];
}

__global__ __launch_bounds__(1024) void scan_top_kernel(int* partials, int nparts)
{
    __shared__ int s[1024];
    int t = threadIdx.x;
    int mine = (t < nparts) ? partials[t] : 0;
    s[t] = mine;
    for (int off = 1; off < 1024; off <<= 1) {
        __syncthreads();
        int v = (t >= off) ? s[t - off] : 0;
        __syncthreads();
        s[t] += v;
    }
    if (t < nparts) partials[t] = s[t] - mine;  // exclusive
}

// in-place: counts -> exclusive offsets
__global__ void scan_final_kernel(int* __restrict__ counts_offsets,
                                  const int* __restrict__ partials, int n)
{
    __shared__ int s[SCAN_BLOCK];
    int t = threadIdx.x;
    int i = blockIdx.x * SCAN_BLOCK + t;
    int mine = (i < n) ? counts_offsets[i] : 0;
    s[t] = mine;
    for (int off = 1; off < SCAN_BLOCK; off <<= 1) {
        __syncthreads();
        int v = (t >= off) ? s[t - off] : 0;
        __syncthreads();
        s[t] += v;
    }
    if (i < n) counts_offsets[i] = s[t] - mine + partials[blockIdx.x];
}

// ---------------- bucket cursor + flag init ----------------
__global__ void cursor_init_kernel(const int* __restrict__ offsets,
                                   int* __restrict__ cursor,
                                   int* __restrict__ flags,
                                   int n_buckets, int n_nodes)
{
    int b = blockIdx.x * blockDim.x + threadIdx.x;
    if (b < n_buckets) {
        int r = b * RPB;
        if (r > n_nodes) r = n_nodes;
        cursor[b] = offsets[r];
        flags[b]  = 0;
    }
}

// ---------------- scatter edges into 16-row bucket streams ----------------
// rec = [ val:f32 (hi32) | localrow:bits17-20 | col:bits0-16 (lo32) ]
__global__ void scatter_kernel(const int* __restrict__ rows,
                               const int* __restrict__ cols,
                               const float* __restrict__ vals,
                               int* __restrict__ cursor,
                               ull* __restrict__ recs,
                               int n_edges)
{
    int i = blockIdx.x * blockDim.x + threadIdx.x;
    if (i >= n_edges) return;
    const int   r = rows[i];
    const int   c = cols[i];
    const float v = vals[i];
    const unsigned lo = ((unsigned)(r & (RPB - 1)) << 17) | (unsigned)c;
    const int pos = atomicAdd(&cursor[r >> 4], 1);
    recs[pos] = ((ull)__float_as_uint(v) << 32) | (ull)lo;
}

// ---------------- in-place within-bucket sort (to full row order) ----------------
__global__ __launch_bounds__(256) void bucket_sort_kernel(
    ull* __restrict__ recs,
    const int* __restrict__ offsets,
    int* __restrict__ flags,
    int n_buckets, int n_nodes)
{
    __shared__ ull stage[SORT_CAP];
    __shared__ int cur[RPB];
    const int b  = blockIdx.x;
    const int t  = threadIdx.x;
    const int r0 = b * RPB;
    const int r1 = (r0 + RPB <= n_nodes) ? r0 + RPB : n_nodes;

    const int seg0 = offsets[r0];
    const int seg1 = offsets[r1];
    const int len  = seg1 - seg0;

    if (len > SORT_CAP) {            // impossible for uniform data; leave unsorted
        if (t == 0) flags[b] = 1;
        return;
    }
    if (t < RPB) {
        int r = r0 + t;
        cur[t] = ((r <= n_nodes) ? offsets[r] : seg1) - seg0;
    }
    for (int i = t; i < len; i += 256) stage[i] = recs[seg0 + i];
    __syncthreads();
    for (int i = t; i < len; i += 256) {
        const ull rec = stage[i];
        const int lr  = (int)((rec >> 17) & (RPB - 1));
        const int p   = atomicAdd(&cur[lr], 1);
        recs[seg0 + p] = rec;
    }
}

// ---------------- CSR SpMM: one wave per row, lane = feature ----------------
__global__ __launch_bounds__(256) void spmm_csr_kernel(
    const float* __restrict__ x,
    const int*   __restrict__ offsets,
    const ull*   __restrict__ recs,
    const int*   __restrict__ flags,
    float*       __restrict__ out,
    int n_nodes)
{
    const int row  = blockIdx.x * 4 + (threadIdx.x >> 6);
    const int lane = threadIdx.x & 63;
    if (row >= n_nodes) return;

    float acc = 0.f;

    if (__builtin_expect(flags[row >> 4], 0)) {
        // safety path: bucket left unsorted — scan whole bucket, filter my row
        const int b  = row >> 4;
        int r1 = b * RPB + RPB; if (r1 > n_nodes) r1 = n_nodes;
        const int s = offsets[b * RPB];
        const int e = offsets[r1];
        const int lr = row & (RPB - 1);
        for (int j = s; j < e; ++j) {
            const ull rec = recs[j];
            if ((int)((rec >> 17) & (RPB - 1)) == lr) {
                const int   c = (int)((unsigned)rec & 0x1FFFF);
                const float v = __uint_as_float((unsigned)(rec >> 32));
                acc += v * x[(size_t)c * D + lane];
            }
        }
    } else {
        const int s = offsets[row];
        const int e = offsets[row + 1];
        int j = s;
        for (; j + 8 <= e; j += 8) {
            float vv[8], xv[8];
            #pragma unroll
            for (int k = 0; k < 8; ++k) {
                const ull rec = recs[j + k];
                vv[k] = __uint_as_float((unsigned)(rec >> 32));
                const int c = (int)((unsigned)rec & 0x1FFFF);
                xv[k] = x[(size_t)c * D + lane];
            }
            #pragma unroll
            for (int k = 0; k < 8; ++k) acc += vv[k] * xv[k];
        }
        for (; j < e; ++j) {
            const ull rec = recs[j];
            const float v = __uint_as_float((unsigned)(rec >> 32));
            const int   c = (int)((unsigned)rec & 0x1FFFF);
            acc += v * x[(size_t)c * D + lane];
        }
    }
    out[(size_t)row * D + lane] = acc;
}

static inline size_t align16(size_t v) { return (v + 15) & ~(size_t)15; }

extern "C" void kernel_launch(void* const* d_in, const int* in_sizes, int n_in,
                              void* d_out, int out_size, void* d_ws, size_t ws_size,
                              hipStream_t stream)
{
    // setup_inputs order: t, x, edge_row, edge_col, edge_val
    const float* x        = (const float*)d_in[1];
    const int*   edge_row = (const int*)d_in[2];
    const int*   edge_col = (const int*)d_in[3];
    const float* edge_val = (const float*)d_in[4];
    float*       out      = (float*)d_out;

    const int n_edges   = in_sizes[2];
    const int n_nodes   = out_size / D;
    const int n_buckets = (n_nodes + RPB - 1) / RPB;
    const int nscan     = n_nodes + 1;
    const int nparts    = (nscan + SCAN_BLOCK - 1) / SCAN_BLOCK;

    // workspace carve
    const size_t off_recs    = 0;                                              // n_edges * 8
    const size_t off_offsets = align16(off_recs + (size_t)n_edges * 8);        // nscan ints
    const size_t off_cursor  = align16(off_offsets + (size_t)nscan * 4);       // n_buckets ints
    const size_t off_flags   = align16(off_cursor + (size_t)n_buckets * 4);    // n_buckets ints
    const size_t off_parts   = align16(off_flags + (size_t)n_buckets * 4);     // <=1024 ints
    const size_t ws_needed   = off_parts + 1024 * 4;

    if (ws_size < ws_needed || nparts > 1024 || n_nodes > (1 << 17)) {
        hipMemsetAsync(out, 0, (size_t)out_size * sizeof(float), stream);
        const int n_blocks = (n_edges + 3) / 4;
        spmm_atomic_kernel<<<n_blocks, 256, 0, stream>>>(
            x, edge_row, edge_col, edge_val, out, n_edges);
        return;
    }

    char* ws = (char*)d_ws;
    ull*  recs    = (ull*)(ws + off_recs);
    int*  offsets = (int*)(ws + off_offsets);
    int*  cursor  = (int*)(ws + off_cursor);
    int*  flags   = (int*)(ws + off_flags);
    int*  parts   = (int*)(ws + off_parts);

    // 1. zero row counts
    hipMemsetAsync(offsets, 0, (size_t)nscan * sizeof(int), stream);

    // 2. row histogram
    const int eb = (n_edges + 255) / 256;
    hist_kernel<<<eb, 256, 0, stream>>>(edge_row, offsets, n_edges);

    // 3. exclusive scan: counts -> offsets (in place)
    scan_partial_kernel<<<nparts, SCAN_BLOCK, 0, stream>>>(offsets, parts, nscan);
    scan_top_kernel<<<1, 1024, 0, stream>>>(parts, nparts);
    scan_final_kernel<<<nparts, SCAN_BLOCK, 0, stream>>>(offsets, parts, nscan);

    // 4. bucket cursors + flags
    cursor_init_kernel<<<(n_buckets + 255) / 256, 256, 0, stream>>>(
        offsets, cursor, flags, n_buckets, n_nodes);

    // 5. scatter into bucket streams (dense append, L2-friendly)
    scatter_kernel<<<eb, 256, 0, stream>>>(edge_row, edge_col, edge_val,
                                           cursor, recs, n_edges);

    // 6. in-place within-bucket sort -> full row order
    bucket_sort_kernel<<<n_buckets, 256, 0, stream>>>(
        recs, offsets, flags, n_buckets, n_nodes);

    // 7. CSR SpMM: one wave per row (max TLP shape — 100k waves)
    spmm_csr_kernel<<<(n_nodes + 3) / 4, 256, 0, stream>>>(
        x, offsets, recs, flags, out, n_nodes);
}

// Round 6
// 500.456 us; speedup vs baseline: 3.6069x; 1.0201x over previous
//
#include <hip/hip_runtime.h>
#include <hip/hip_bf16.h>

#define D 64
#define RPB 16                  // rows per bucket (4-bit local row)
#define NPART 8                 // per-XCD stream partitions (blockIdx & 7)
#define SORT_CAP 2048           // LDS staging capacity (recs) for in-place bucket sort
#define SCAN_BLOCK 256

typedef unsigned long long ull;

// ---------------- fallback: round-1 atomic kernel ----------------
__global__ __launch_bounds__(256) void spmm_atomic_kernel(
    const float* __restrict__ x,
    const int*   __restrict__ edge_row,
    const int*   __restrict__ edge_col,
    const float* __restrict__ edge_val,
    float*       __restrict__ out,
    int n_edges)
{
    const int gtid = blockIdx.x * blockDim.x + threadIdx.x;
    const int wave = gtid >> 6;
    const int lane = threadIdx.x & 63;
    if (wave >= n_edges) return;
    const int   r = edge_row[wave];
    const int   c = edge_col[wave];
    const float v = edge_val[wave];
    atomicAdd(&out[(size_t)r * D + lane], v * x[(size_t)c * D + lane]);
}

// ---------------- (bucket, partition) histogram, partition-major layout ----------------
// p = blockIdx & 7 approximates the XCD (round-robin dispatch), so each XCD's
// atomics stay on its own slice of the counter array (no cross-XCD line bounce).
__global__ void hist_kernel(const int* __restrict__ rows,
                            int* __restrict__ counts_pm,   // [NPART][n_buckets]
                            int n_edges, int n_buckets)
{
    const int i = blockIdx.x * blockDim.x + threadIdx.x;
    const int p = blockIdx.x & (NPART - 1);
    if (i < n_edges)
        atomicAdd(&counts_pm[p * n_buckets + (rows[i] >> 4)], 1);
}

// ---------------- blocked exclusive scan over keys k = bucket*8 + p ----------------
// reads counts permuted (partition-major), writes bucket-major bp_offsets
// (so a bucket's 8 sub-segments are contiguous) + partition-major cursor.
__global__ void scan_partial_kernel(const int* __restrict__ counts_pm,
                                    int* __restrict__ partials,
                                    int nscan, int n_buckets)
{
    __shared__ int s[SCAN_BLOCK];
    const int k = blockIdx.x * SCAN_BLOCK + threadIdx.x;
    int v = 0;
    if (k < n_buckets * NPART)
        v = counts_pm[(k & (NPART - 1)) * n_buckets + (k >> 3)];
    s[threadIdx.x] = v;
    __syncthreads();
    for (int off = SCAN_BLOCK / 2; off > 0; off >>= 1) {
        if (threadIdx.x < off) s[threadIdx.x] += s[threadIdx.x + off];
        __syncthreads();
    }
    if (threadIdx.x == 0) partials[blockIdx.x] = s[0];
}

__global__ __launch_bounds__(1024) void scan_top_kernel(int* partials, int nparts)
{
    __shared__ int s[1024];
    int t = threadIdx.x;
    int mine = (t < nparts) ? partials[t] : 0;
    s[t] = mine;
    for (int off = 1; off < 1024; off <<= 1) {
        __syncthreads();
        int v = (t >= off) ? s[t - off] : 0;
        __syncthreads();
        s[t] += v;
    }
    if (t < nparts) partials[t] = s[t] - mine;  // exclusive
}

__global__ void scan_final_kernel(const int* __restrict__ counts_pm,
                                  const int* __restrict__ partials,
                                  int* __restrict__ bp_offsets,   // [n_buckets*8 + 1]
                                  int* __restrict__ cursor_pm,    // [NPART][n_buckets]
                                  int nscan, int n_buckets)
{
    __shared__ int s[SCAN_BLOCK];
    const int t = threadIdx.x;
    const int k = blockIdx.x * SCAN_BLOCK + t;
    int mine = 0;
    if (k < n_buckets * NPART)
        mine = counts_pm[(k & (NPART - 1)) * n_buckets + (k >> 3)];
    s[t] = mine;
    for (int off = 1; off < SCAN_BLOCK; off <<= 1) {
        __syncthreads();
        int v = (t >= off) ? s[t - off] : 0;
        __syncthreads();
        s[t] += v;
    }
    const int excl = s[t] - mine + partials[blockIdx.x];
    if (k < nscan) {
        bp_offsets[k] = excl;
        if (k < n_buckets * NPART)
            cursor_pm[(k & (NPART - 1)) * n_buckets + (k >> 3)] = excl;
    }
}

// ---------------- scatter edges into XCD-local bucket streams ----------------
// rec = [ val:f32 (hi32) | localrow:bits17-20 | col:bits0-16 (lo32) ]
// Same grid geometry + same p = blockIdx&7 as hist_kernel -> counts match exactly.
__global__ void scatter_kernel(const int* __restrict__ rows,
                               const int* __restrict__ cols,
                               const float* __restrict__ vals,
                               int* __restrict__ cursor_pm,
                               ull* __restrict__ recs,
                               int n_edges, int n_buckets)
{
    const int i = blockIdx.x * blockDim.x + threadIdx.x;
    const int p = blockIdx.x & (NPART - 1);
    if (i >= n_edges) return;
    const int   r = rows[i];
    const int   c = cols[i];
    const float v = vals[i];
    const unsigned lo = ((unsigned)(r & (RPB - 1)) << 17) | (unsigned)c;
    const int pos = atomicAdd(&cursor_pm[p * n_buckets + (r >> 4)], 1);
    recs[pos] = ((ull)__float_as_uint(v) << 32) | (ull)lo;
}

// ---------------- in-place within-bucket sort + row-offset emission ----------------
__global__ __launch_bounds__(256) void bucket_sort_kernel(
    ull* __restrict__ recs,
    const int* __restrict__ bp_offsets,
    int* __restrict__ offsets_row,   // [n_nodes + 1]
    int* __restrict__ flags,
    int n_buckets, int n_nodes)
{
    __shared__ ull stage[SORT_CAP];
    __shared__ int cnt[RPB];
    __shared__ int cur[RPB];
    const int b = blockIdx.x;
    const int t = threadIdx.x;

    const int seg0 = bp_offsets[b * NPART];
    const int seg1 = bp_offsets[b * NPART + NPART];
    const int len  = seg1 - seg0;

    if (len > SORT_CAP) {            // ~infeasible for uniform data; leave unsorted
        if (t == 0) flags[b] = 1;
        return;
    }
    if (t < RPB) cnt[t] = 0;
    __syncthreads();

    // stage + local row histogram
    for (int i = t; i < len; i += 256) {
        const ull rr = recs[seg0 + i];
        stage[i] = rr;
        atomicAdd(&cnt[(int)((rr >> 17) & (RPB - 1))], 1);
    }
    __syncthreads();

    if (t == 0) {
        int s = 0;
        #pragma unroll
        for (int k = 0; k < RPB; ++k) { cur[k] = s; s += cnt[k]; }
    }
    __syncthreads();

    // emit global row offsets (sentinel r0+RPB duplicated by neighbor — benign)
    const int r0 = b * RPB;
    if (t <= RPB) {
        const int r = r0 + t;
        if (r <= n_nodes)
            offsets_row[r] = seg0 + ((t == RPB) ? len : cur[t]);
    }
    __syncthreads();

    // permute to full row order
    for (int i = t; i < len; i += 256) {
        const ull rr = stage[i];
        const int lr = (int)((rr >> 17) & (RPB - 1));
        const int p  = atomicAdd(&cur[lr], 1);
        recs[seg0 + p] = rr;
    }
}

// ---------------- CSR SpMM: one wave per row, lane = feature ----------------
__global__ __launch_bounds__(256) void spmm_csr_kernel(
    const float* __restrict__ x,
    const int*   __restrict__ offsets_row,
    const int*   __restrict__ bp_offsets,
    const ull*   __restrict__ recs,
    const int*   __restrict__ flags,
    float*       __restrict__ out,
    int n_nodes)
{
    const int row  = blockIdx.x * 4 + (threadIdx.x >> 6);
    const int lane = threadIdx.x & 63;
    if (row >= n_nodes) return;

    float acc = 0.f;
    const int b = row >> 4;

    if (__builtin_expect(flags[b], 0)) {
        // safety path: bucket left unsorted — scan whole bucket, filter my row
        const int s  = bp_offsets[b * NPART];
        const int e  = bp_offsets[b * NPART + NPART];
        const int lr = row & (RPB - 1);
        for (int j = s; j < e; ++j) {
            const ull rec = recs[j];
            if ((int)((rec >> 17) & (RPB - 1)) == lr) {
                const int   c = (int)((unsigned)rec & 0x1FFFF);
                const float v = __uint_as_float((unsigned)(rec >> 32));
                acc += v * x[(size_t)c * D + lane];
            }
        }
    } else {
        const int s = offsets_row[row];
        const int e = offsets_row[row + 1];
        int j = s;
        for (; j + 8 <= e; j += 8) {
            float vv[8], xv[8];
            #pragma unroll
            for (int k = 0; k < 8; ++k) {
                const ull rec = recs[j + k];
                vv[k] = __uint_as_float((unsigned)(rec >> 32));
                const int c = (int)((unsigned)rec & 0x1FFFF);
                xv[k] = x[(size_t)c * D + lane];
            }
            #pragma unroll
            for (int k = 0; k < 8; ++k) acc += vv[k] * xv[k];
        }
        for (; j < e; ++j) {
            const ull rec = recs[j];
            const float v = __uint_as_float((unsigned)(rec >> 32));
            const int   c = (int)((unsigned)rec & 0x1FFFF);
            acc += v * x[(size_t)c * D + lane];
        }
    }
    out[(size_t)row * D + lane] = acc;
}

static inline size_t align16(size_t v) { return (v + 15) & ~(size_t)15; }

extern "C" void kernel_launch(void* const* d_in, const int* in_sizes, int n_in,
                              void* d_out, int out_size, void* d_ws, size_t ws_size,
                              hipStream_t stream)
{
    // setup_inputs order: t, x, edge_row, edge_col, edge_val
    const float* x        = (const float*)d_in[1];
    const int*   edge_row = (const int*)d_in[2];
    const int*   edge_col = (const int*)d_in[3];
    const float* edge_val = (const float*)d_in[4];
    float*       out      = (float*)d_out;

    const int n_edges   = in_sizes[2];
    const int n_nodes   = out_size / D;
    const int n_buckets = (n_nodes + RPB - 1) / RPB;
    const int nscan     = n_buckets * NPART + 1;
    const int nparts    = (nscan + SCAN_BLOCK - 1) / SCAN_BLOCK;

    // workspace carve
    const size_t off_recs    = 0;                                               // n_edges * 8
    const size_t off_counts  = align16(off_recs + (size_t)n_edges * 8);         // n_buckets*8 ints
    const size_t off_bpoffs  = align16(off_counts + (size_t)n_buckets * NPART * 4); // nscan ints
    const size_t off_cursor  = align16(off_bpoffs + (size_t)nscan * 4);         // n_buckets*8 ints
    const size_t off_rowoffs = align16(off_cursor + (size_t)n_buckets * NPART * 4); // n_nodes+1 ints
    const size_t off_flags   = align16(off_rowoffs + (size_t)(n_nodes + 1) * 4);    // n_buckets ints
    const size_t off_parts   = align16(off_flags + (size_t)n_buckets * 4);      // <=1024 ints
    const size_t ws_needed   = off_parts + 1024 * 4;

    if (ws_size < ws_needed || nparts > 1024 || n_nodes > (1 << 17)) {
        hipMemsetAsync(out, 0, (size_t)out_size * sizeof(float), stream);
        const int n_blocks = (n_edges + 3) / 4;
        spmm_atomic_kernel<<<n_blocks, 256, 0, stream>>>(
            x, edge_row, edge_col, edge_val, out, n_edges);
        return;
    }

    char* ws = (char*)d_ws;
    ull*  recs        = (ull*)(ws + off_recs);
    int*  counts_pm   = (int*)(ws + off_counts);
    int*  bp_offsets  = (int*)(ws + off_bpoffs);
    int*  cursor_pm   = (int*)(ws + off_cursor);
    int*  offsets_row = (int*)(ws + off_rowoffs);
    int*  flags       = (int*)(ws + off_flags);
    int*  parts       = (int*)(ws + off_parts);

    // 1. zero counters + flags
    hipMemsetAsync(counts_pm, 0, (size_t)n_buckets * NPART * sizeof(int), stream);
    hipMemsetAsync(flags, 0, (size_t)n_buckets * sizeof(int), stream);

    // 2. (bucket, partition) histogram
    const int eb = (n_edges + 255) / 256;
    hist_kernel<<<eb, 256, 0, stream>>>(edge_row, counts_pm, n_edges, n_buckets);

    // 3. exclusive scan over (bucket, partition) keys
    scan_partial_kernel<<<nparts, SCAN_BLOCK, 0, stream>>>(counts_pm, parts, nscan, n_buckets);
    scan_top_kernel<<<1, 1024, 0, stream>>>(parts, nparts);
    scan_final_kernel<<<nparts, SCAN_BLOCK, 0, stream>>>(
        counts_pm, parts, bp_offsets, cursor_pm, nscan, n_buckets);

    // 4. scatter into XCD-local bucket streams
    scatter_kernel<<<eb, 256, 0, stream>>>(edge_row, edge_col, edge_val,
                                           cursor_pm, recs, n_edges, n_buckets);

    // 5. in-place within-bucket sort -> full row order + row offsets
    bucket_sort_kernel<<<n_buckets, 256, 0, stream>>>(
        recs, bp_offsets, offsets_row, flags, n_buckets, n_nodes);

    // 6. CSR SpMM: one wave per row (max TLP shape — 100k waves)
    spmm_csr_kernel<<<(n_nodes + 3) / 4, 256, 0, stream>>>(
        x, offsets_row, bp_offsets, recs, flags, out, n_nodes);
}